// Round 3
// baseline (93.726 us; speedup 1.0000x reference)
//
#include <hip/hip_runtime.h>

// FFM pairwise cross-term layer.
// out[b, p, d] = W[jj[p], adj[b, ii[p]], d] * W[ii[p], adj[b, jj[p]], d]
// B=8192, F=23, P=F*(F-1)/2=253, D=32, VOCAB=190001, fp32 throughout.
//
// R3 change vs R2: plain stores instead of __builtin_nontemporal_store
// (A/B test: NT bypass suspected of halving effective write BW; dur was
// 80.7 us = 2x the 39 us write floor at the fill kernel's 6.8 TB/s).

#define NF 23
#define NP 253             // 23*22/2
#define VOCAB 190001
#define F4_PER_B (NP * 8)  // 253 pairs * 8 float4 (D=32)

typedef float f32x4 __attribute__((ext_vector_type(4)));

__global__ __launch_bounds__(256) void ffm_cross_kernel(
    const int* __restrict__ x,
    const int* __restrict__ offs,
    const float* __restrict__ W,
    float* __restrict__ out)
{
    __shared__ int adj_s[NF];
    __shared__ unsigned int rowA[NP];  // float4-index of W[jj, adj[ii], 0]
    __shared__ unsigned int rowB[NP];  // float4-index of W[ii, adj[jj], 0]

    const int b   = blockIdx.x;
    const int tid = threadIdx.x;

    if (tid < NF) adj_s[tid] = x[b * NF + tid] + offs[tid];
    __syncthreads();

    if (tid < NP) {
        // unrank pair p -> (i, j), row-major triu order: (0,1),(0,2),...,(21,22)
        int rem = tid, i = 0;
        while (rem >= (NF - 1 - i)) { rem -= (NF - 1 - i); ++i; }
        int j = i + 1 + rem;
        // max index: (22*190001 + 190000)*8 < 2^32 -> u32 ok
        rowA[tid] = ((unsigned)j * (unsigned)VOCAB + (unsigned)adj_s[i]) * 8u;
        rowB[tid] = ((unsigned)i * (unsigned)VOCAB + (unsigned)adj_s[j]) * 8u;
    }
    __syncthreads();

    const f32x4* __restrict__ W4 = reinterpret_cast<const f32x4*>(W);
    f32x4* __restrict__ O4 =
        reinterpret_cast<f32x4*>(out) + (size_t)b * F4_PER_B;

    #pragma unroll
    for (int k = 0; k < 8; ++k) {
        int idx = tid + k * 256;
        if (idx < F4_PER_B) {
            int p  = idx >> 3;
            int d4 = idx & 7;
            f32x4 a = W4[(size_t)rowA[p] + d4];
            f32x4 c = W4[(size_t)rowB[p] + d4];
            O4[idx] = a * c;
        }
    }
}

extern "C" void kernel_launch(void* const* d_in, const int* in_sizes, int n_in,
                              void* d_out, int out_size, void* d_ws, size_t ws_size,
                              hipStream_t stream)
{
    const int*   x    = (const int*)d_in[0];    // [8192, 23] int32
    const int*   offs = (const int*)d_in[1];    // [23] int32
    const float* W    = (const float*)d_in[2];  // [23, 190001, 32] fp32
    float*       out  = (float*)d_out;          // [8192, 253, 32] fp32

    ffm_cross_kernel<<<8192, 256, 0, stream>>>(x, offs, W, out);
}

// Round 4
// 54.293 us; speedup vs baseline: 1.7263x; 1.7263x over previous
//
#include <hip/hip_runtime.h>

// FFM pairwise cross-term layer.
// out[b, p, d] = W[jj[p], adj[b, ii[p]], d] * W[ii[p], adj[b, jj[p]], d]
// B=8192, F=23, P=253, D=32, VOCAB=190001, fp32.
//
// R4: XCD-aware pair partitioning. Each pair owns 2 disjoint 100-row W
// stripes (25.6 KB). Chunk pairs into 8 groups of <=32, pin each group to
// one XCD (blockIdx % 8 round-robins over XCDs) -> per-XCD read working set
// ~820 KB, fits the 4 MB per-XCD L2. NT stores keep the 265 MB write stream
// from thrashing the caches (R2 vs R3 A/B: NT won, 80.7 vs 93.7 us).
// Block = pair-chunk x 8-batch tile: per batch elem writes 4 KB contiguous.

#define NF 23
#define NP 253
#define VOCAB 190001
#define PPC 32           // pairs per chunk (last chunk has 29)
#define NCHUNK 8
#define TILE_B 8

typedef float f32x4 __attribute__((ext_vector_type(4)));

__global__ __launch_bounds__(256) void ffm_cross_kernel(
    const int* __restrict__ x,
    const int* __restrict__ offs,
    const float* __restrict__ W,
    float* __restrict__ out)
{
    const int chunk = blockIdx.x & 7;      // -> XCD id (round-robin dispatch)
    const int tile  = blockIdx.x >> 3;
    const int p0    = chunk * PPC;
    const int np    = (NP - p0 < PPC) ? (NP - p0) : PPC;  // 32 or 29
    const int b0    = tile * TILE_B;
    const int tid   = threadIdx.x;

    __shared__ int      adj_s[TILE_B][NF];
    __shared__ unsigned rowA[TILE_B][PPC];  // f4-index of W[j, adj[b,i]]
    __shared__ unsigned rowB[TILE_B][PPC];  // f4-index of W[i, adj[b,j]]

    if (tid < TILE_B * NF) {
        int bl = tid / NF, f = tid % NF;
        adj_s[bl][f] = x[(b0 + bl) * NF + f] + offs[f];
    }
    __syncthreads();

    for (int e = tid; e < TILE_B * PPC; e += 256) {
        int bl = e >> 5, pl = e & 31;
        if (pl < np) {
            int p = p0 + pl;
            // unrank triu pair: (0,1),(0,2),...,(21,22)
            int rem = p, i = 0;
            while (rem >= NF - 1 - i) { rem -= NF - 1 - i; ++i; }
            int j = i + 1 + rem;
            rowA[bl][pl] = ((unsigned)j * (unsigned)VOCAB + (unsigned)adj_s[bl][i]) * 8u;
            rowB[bl][pl] = ((unsigned)i * (unsigned)VOCAB + (unsigned)adj_s[bl][j]) * 8u;
        }
    }
    __syncthreads();

    const f32x4* __restrict__ W4 = reinterpret_cast<const f32x4*>(W);
    f32x4* __restrict__ O4 = reinterpret_cast<f32x4*>(out);

    // idx = ((bl*PPC) + pl)*8 + d4, 2048 total per block
    #pragma unroll
    for (int k = 0; k < 8; ++k) {
        int idx = tid + k * 256;
        int d4 = idx & 7;
        int pl = (idx >> 3) & 31;
        int bl = idx >> 8;
        if (pl < np) {
            f32x4 a = W4[(size_t)rowA[bl][pl] + d4];
            f32x4 c = W4[(size_t)rowB[bl][pl] + d4];
            f32x4 r = a * c;
            size_t o = (size_t)(b0 + bl) * (NP * 8) + (size_t)(p0 + pl) * 8 + d4;
            __builtin_nontemporal_store(r, &O4[o]);
        }
    }
}

extern "C" void kernel_launch(void* const* d_in, const int* in_sizes, int n_in,
                              void* d_out, int out_size, void* d_ws, size_t ws_size,
                              hipStream_t stream)
{
    const int*   x    = (const int*)d_in[0];    // [8192, 23] int32
    const int*   offs = (const int*)d_in[1];    // [23] int32
    const float* W    = (const float*)d_in[2];  // [23, 190001, 32] fp32
    float*       out  = (float*)d_out;          // [8192, 253, 32] fp32

    ffm_cross_kernel<<<NCHUNK * (8192 / TILE_B), 256, 0, stream>>>(x, offs, W, out);
}